// Round 1
// baseline (4077.514 us; speedup 1.0000x reference)
//
#include <hip/hip_runtime.h>
#include <math.h>

#define N_NODES 50000
#define N_EDGES 800000
#define D_IN 128
#define D1 150
#define D2 100
#define D_OUT 64

// ---------------- degree counting ----------------
__global__ void deg_kernel(const int* __restrict__ src, const int* __restrict__ dst,
                           float* __restrict__ deg_out, float* __restrict__ deg_in) {
    int e = blockIdx.x * blockDim.x + threadIdx.x;
    if (e < N_EDGES) {
        atomicAdd(&deg_out[src[e]], 1.0f);
        atomicAdd(&deg_in[dst[e]], 1.0f);
    }
}

// ---------------- scatter 1: agg[dst] += x[src] * norm_out[src] ----------------
// one thread per (edge, float4-chunk); 32 chunks cover 128 floats
__global__ void scatter_x(const float* __restrict__ x, const int* __restrict__ src,
                          const int* __restrict__ dst, const float* __restrict__ deg_out,
                          float* __restrict__ agg) {
    int item = blockIdx.x * blockDim.x + threadIdx.x;   // < 25.6M, fits int
    if (item >= N_EDGES * 32) return;
    int e = item >> 5;
    int c = item & 31;
    int s = src[e], d = dst[e];
    float no = rsqrtf(fmaxf(deg_out[s], 1.0f));
    float4 v = ((const float4*)x)[s * 32 + c];
    float* o = agg + (size_t)d * D_IN + c * 4;
    atomicAdd(o + 0, v.x * no);
    atomicAdd(o + 1, v.y * no);
    atomicAdd(o + 2, v.z * no);
    atomicAdd(o + 3, v.w * no);
}

// ---------------- scatter 2: ns[dst] += p[src]  (p = h1 @ Wn, 100 floats) ----------------
__global__ void scatter_p(const float* __restrict__ p, const int* __restrict__ src,
                          const int* __restrict__ dst, float* __restrict__ ns) {
    int item = blockIdx.x * blockDim.x + threadIdx.x;   // < 20M
    if (item >= N_EDGES * 25) return;
    int e = item / 25;
    int c = item - e * 25;
    int s = src[e], d = dst[e];
    float4 v = ((const float4*)p)[s * 25 + c];
    float* o = ns + (size_t)d * D2 + c * 4;
    atomicAdd(o + 0, v.x);
    atomicAdd(o + 1, v.y);
    atomicAdd(o + 2, v.z);
    atomicAdd(o + 3, v.w);
}

// ---------------- GEMM1: h1 = elu(norm_in * (agg @ W1) + b1) ----------------
// thread j holds W1[:,j] in registers; A-row loads are block-uniform (-> s_load broadcast)
#define NPB 32
__global__ void gemm1_kernel(const float* __restrict__ agg, const float* __restrict__ deg_in,
                             const float* __restrict__ W1, const float* __restrict__ b1,
                             float* __restrict__ h1) {
    int j = threadIdx.x;             // 0..191
    int jc = j < D1 ? j : D1 - 1;
    float w[D_IN];
#pragma unroll
    for (int k = 0; k < D_IN; ++k) w[k] = W1[k * D1 + jc];
    float bias = b1[jc];
    int n0 = blockIdx.x * NPB;
    int n1 = n0 + NPB; if (n1 > N_NODES) n1 = N_NODES;
    for (int n = n0; n < n1; ++n) {
        const float4* arow = (const float4*)(agg + (size_t)n * D_IN);
        float acc = 0.0f;
#pragma unroll
        for (int k4 = 0; k4 < D_IN / 4; ++k4) {
            float4 a = arow[k4];
            acc += a.x * w[4 * k4 + 0];
            acc += a.y * w[4 * k4 + 1];
            acc += a.z * w[4 * k4 + 2];
            acc += a.w * w[4 * k4 + 3];
        }
        if (j < D1) {
            float ni = rsqrtf(fmaxf(deg_in[n], 1.0f));
            float v = acc * ni + bias;
            h1[(size_t)n * D1 + j] = v > 0.0f ? v : expm1f(v);
        }
    }
}

// ---------------- GEMM-P: p = h1 @ Wn (no bias/act) ----------------
__global__ void gemmP_kernel(const float* __restrict__ h1, const float* __restrict__ Wn,
                             float* __restrict__ p) {
    int j = threadIdx.x;             // 0..127
    int jc = j < D2 ? j : D2 - 1;
    float w[D1];
#pragma unroll
    for (int k = 0; k < D1; ++k) w[k] = Wn[k * D2 + jc];
    int n0 = blockIdx.x * NPB;
    int n1 = n0 + NPB; if (n1 > N_NODES) n1 = N_NODES;
    for (int n = n0; n < n1; ++n) {
        const float* row = h1 + (size_t)n * D1;
        float acc = 0.0f;
#pragma unroll
        for (int k = 0; k < D1; ++k) acc += row[k] * w[k];
        if (j < D2) p[(size_t)n * D2 + j] = acc;
    }
}

// ---------------- GEMM2: h2 = elu(h1 @ Ws + ns/deg_in + b2) ----------------
__global__ void gemm2_kernel(const float* __restrict__ h1, const float* __restrict__ ns,
                             const float* __restrict__ deg_in, const float* __restrict__ Ws,
                             const float* __restrict__ b2, float* __restrict__ h2) {
    int j = threadIdx.x;             // 0..127
    int jc = j < D2 ? j : D2 - 1;
    float w[D1];
#pragma unroll
    for (int k = 0; k < D1; ++k) w[k] = Ws[k * D2 + jc];
    float bias = b2[jc];
    int n0 = blockIdx.x * NPB;
    int n1 = n0 + NPB; if (n1 > N_NODES) n1 = N_NODES;
    for (int n = n0; n < n1; ++n) {
        const float* row = h1 + (size_t)n * D1;
        float acc = bias;
#pragma unroll
        for (int k = 0; k < D1; ++k) acc += row[k] * w[k];
        float inv = 1.0f / fmaxf(deg_in[n], 1.0f);
        float v = acc + ns[(size_t)n * D2 + jc] * inv;
        if (j < D2) h2[(size_t)n * D2 + j] = v > 0.0f ? v : expm1f(v);
    }
}

// ---------------- GEMM3: out = elu(h2 @ W3 + b3) ----------------
#define NPB3 32
__global__ void gemm3_kernel(const float* __restrict__ h2, const float* __restrict__ W3,
                             const float* __restrict__ b3, float* __restrict__ out) {
    int j = threadIdx.x;             // 0..63, all active
    float w[D2];
#pragma unroll
    for (int k = 0; k < D2; ++k) w[k] = W3[k * D_OUT + j];
    float bias = b3[j];
    int n0 = blockIdx.x * NPB3;
    int n1 = n0 + NPB3; if (n1 > N_NODES) n1 = N_NODES;
    for (int n = n0; n < n1; ++n) {
        const float4* row = (const float4*)(h2 + (size_t)n * D2);
        float acc = bias;
#pragma unroll
        for (int k4 = 0; k4 < D2 / 4; ++k4) {
            float4 a = row[k4];
            acc += a.x * w[4 * k4 + 0];
            acc += a.y * w[4 * k4 + 1];
            acc += a.z * w[4 * k4 + 2];
            acc += a.w * w[4 * k4 + 3];
        }
        out[(size_t)n * D_OUT + j] = acc > 0.0f ? acc : expm1f(acc);
    }
}

extern "C" void kernel_launch(void* const* d_in, const int* in_sizes, int n_in,
                              void* d_out, int out_size, void* d_ws, size_t ws_size,
                              hipStream_t stream) {
    const float* x  = (const float*)d_in[0];
    const int* src  = (const int*)d_in[1];
    const int* dst  = (const int*)d_in[2];
    const float* W1 = (const float*)d_in[3];
    const float* b1 = (const float*)d_in[4];
    const float* Wn = (const float*)d_in[5];
    const float* Ws = (const float*)d_in[6];
    const float* b2 = (const float*)d_in[7];
    const float* W3 = (const float*)d_in[8];
    const float* b3 = (const float*)d_in[9];
    float* out = (float*)d_out;

    // workspace layout (floats): deg_out N | deg_in N | agg 128N | h1 150N | p 100N | ns 100N
    // h2 overlays agg (dead after gemm1). total = 480N floats = 96 MB.
    float* ws      = (float*)d_ws;
    float* deg_out = ws;
    float* deg_in  = ws + N_NODES;
    float* agg     = ws + 2 * (size_t)N_NODES;
    float* h1      = agg + (size_t)N_NODES * D_IN;
    float* p       = h1 + (size_t)N_NODES * D1;
    float* ns      = p + (size_t)N_NODES * D2;
    float* h2      = agg;   // overlay

    hipMemsetAsync(deg_out, 0, 2 * (size_t)N_NODES * sizeof(float), stream);
    hipMemsetAsync(agg, 0, (size_t)N_NODES * D_IN * sizeof(float), stream);
    hipMemsetAsync(ns, 0, (size_t)N_NODES * D2 * sizeof(float), stream);

    deg_kernel<<<(N_EDGES + 255) / 256, 256, 0, stream>>>(src, dst, deg_out, deg_in);
    scatter_x<<<(N_EDGES * 32) / 256, 256, 0, stream>>>(x, src, dst, deg_out, agg);
    gemm1_kernel<<<(N_NODES + NPB - 1) / NPB, 192, 0, stream>>>(agg, deg_in, W1, b1, h1);
    gemmP_kernel<<<(N_NODES + NPB - 1) / NPB, 128, 0, stream>>>(h1, Wn, p);
    scatter_p<<<(N_EDGES * 25) / 256, 256, 0, stream>>>(p, src, dst, ns);
    gemm2_kernel<<<(N_NODES + NPB - 1) / NPB, 128, 0, stream>>>(h1, ns, deg_in, Ws, b2, h2);
    gemm3_kernel<<<(N_NODES + NPB3 - 1) / NPB3, 64, 0, stream>>>(h2, W3, b3, out);
}

// Round 2
// 1798.323 us; speedup vs baseline: 2.2674x; 2.2674x over previous
//
#include <hip/hip_runtime.h>
#include <math.h>

#define N_NODES 50000
#define N_EDGES 800000
#define D_IN 128
#define D1 150
#define D2 100
#define D_OUT 64

// ---------------- degree counting (int atomics) ----------------
__global__ void count_kernel(const int* __restrict__ src, const int* __restrict__ dst,
                             int* __restrict__ deg_out_cnt, int* __restrict__ deg_in_cnt) {
    int e = blockIdx.x * blockDim.x + threadIdx.x;
    if (e < N_EDGES) {
        atomicAdd(&deg_out_cnt[src[e]], 1);
        atomicAdd(&deg_in_cnt[dst[e]], 1);
    }
}

// ---------------- exclusive scan of deg_in -> row_ptr (single block) ----------------
__global__ void scan_kernel(const int* __restrict__ cnt, int* __restrict__ row_ptr) {
    __shared__ int buf[1024];
    __shared__ int carry_s;
    int t = threadIdx.x;
    if (t == 0) carry_s = 0;
    __syncthreads();
    for (int base = 0; base < N_NODES; base += 1024) {
        int i = base + t;
        int v = (i < N_NODES) ? cnt[i] : 0;
        buf[t] = v;
        __syncthreads();
        for (int off = 1; off < 1024; off <<= 1) {
            int add = (t >= off) ? buf[t - off] : 0;
            __syncthreads();
            buf[t] += add;
            __syncthreads();
        }
        int carry = carry_s;
        if (i < N_NODES) row_ptr[i] = carry + buf[t] - v;   // exclusive
        int total = buf[1023];
        __syncthreads();
        if (t == 0) carry_s = carry + total;
        __syncthreads();
    }
    if (t == 0) row_ptr[N_NODES] = carry_s;
}

// ---------------- CSR fill: bucket edges by dst ----------------
__global__ void fill_kernel(const int* __restrict__ src, const int* __restrict__ dst,
                            const int* __restrict__ row_ptr, int* __restrict__ cursor,
                            int* __restrict__ edge_src) {
    int e = blockIdx.x * blockDim.x + threadIdx.x;
    if (e < N_EDGES) {
        int d = dst[e];
        int pos = atomicAdd(&cursor[d], 1);
        edge_src[row_ptr[d] + pos] = src[e];
    }
}

// ---------------- xs = x * norm_out ----------------
__global__ void prescale_kernel(const float* __restrict__ x, const int* __restrict__ deg_out_cnt,
                                float* __restrict__ xs) {
    int item = blockIdx.x * blockDim.x + threadIdx.x;   // N_NODES*32 float4 chunks
    if (item >= N_NODES * 32) return;
    int n = item >> 5;
    float no = rsqrtf(fmaxf((float)deg_out_cnt[n], 1.0f));
    float4 v = ((const float4*)x)[item];
    v.x *= no; v.y *= no; v.z *= no; v.w *= no;
    ((float4*)xs)[item] = v;
}

// ---------------- gather 1: agg[n] = sum_{e in in(n)} xs[src[e]] ----------------
// one wave per node; lane t holds floats t and t+64
__global__ void gather_x(const float* __restrict__ xs, const int* __restrict__ row_ptr,
                         const int* __restrict__ edge_src, float* __restrict__ agg) {
    int wave = threadIdx.x >> 6;
    int lane = threadIdx.x & 63;
    int n = blockIdx.x * 4 + wave;
    if (n >= N_NODES) return;
    int beg = row_ptr[n], end = row_ptr[n + 1];
    float a0 = 0.0f, a1 = 0.0f;
    for (int e = beg; e < end; ++e) {
        int s = edge_src[e];
        const float* r = xs + (size_t)s * D_IN;
        a0 += r[lane];
        a1 += r[lane + 64];
    }
    agg[(size_t)n * D_IN + lane] = a0;
    agg[(size_t)n * D_IN + lane + 64] = a1;
}

// ---------------- gather 2: ns[n] = sum_{e in in(n)} p[src[e]] ----------------
__global__ void gather_p(const float* __restrict__ p, const int* __restrict__ row_ptr,
                         const int* __restrict__ edge_src, float* __restrict__ ns) {
    int wave = threadIdx.x >> 6;
    int lane = threadIdx.x & 63;
    int n = blockIdx.x * 4 + wave;
    if (n >= N_NODES) return;
    int beg = row_ptr[n], end = row_ptr[n + 1];
    float a0 = 0.0f, a1 = 0.0f;
    for (int e = beg; e < end; ++e) {
        int s = edge_src[e];
        const float* r = p + (size_t)s * D2;
        a0 += r[lane];
        if (lane < D2 - 64) a1 += r[lane + 64];
    }
    ns[(size_t)n * D2 + lane] = a0;
    if (lane < D2 - 64) ns[(size_t)n * D2 + lane + 64] = a1;
}

// ---------------- GEMM1: h1 = elu(norm_in * (agg @ W1) + b1) ----------------
#define NPB 32
__global__ void gemm1_kernel(const float* __restrict__ agg, const int* __restrict__ deg_in_cnt,
                             const float* __restrict__ W1, const float* __restrict__ b1,
                             float* __restrict__ h1) {
    int j = threadIdx.x;             // 0..191
    int jc = j < D1 ? j : D1 - 1;
    float w[D_IN];
#pragma unroll
    for (int k = 0; k < D_IN; ++k) w[k] = W1[k * D1 + jc];
    float bias = b1[jc];
    int n0 = blockIdx.x * NPB;
    int n1 = n0 + NPB; if (n1 > N_NODES) n1 = N_NODES;
    for (int n = n0; n < n1; ++n) {
        const float4* arow = (const float4*)(agg + (size_t)n * D_IN);
        float acc = 0.0f;
#pragma unroll
        for (int k4 = 0; k4 < D_IN / 4; ++k4) {
            float4 a = arow[k4];
            acc += a.x * w[4 * k4 + 0];
            acc += a.y * w[4 * k4 + 1];
            acc += a.z * w[4 * k4 + 2];
            acc += a.w * w[4 * k4 + 3];
        }
        if (j < D1) {
            float ni = rsqrtf(fmaxf((float)deg_in_cnt[n], 1.0f));
            float v = acc * ni + bias;
            h1[(size_t)n * D1 + j] = v > 0.0f ? v : expm1f(v);
        }
    }
}

// ---------------- GEMM-P: p = h1 @ Wn ----------------
__global__ void gemmP_kernel(const float* __restrict__ h1, const float* __restrict__ Wn,
                             float* __restrict__ p) {
    int j = threadIdx.x;             // 0..127
    int jc = j < D2 ? j : D2 - 1;
    float w[D1];
#pragma unroll
    for (int k = 0; k < D1; ++k) w[k] = Wn[k * D2 + jc];
    int n0 = blockIdx.x * NPB;
    int n1 = n0 + NPB; if (n1 > N_NODES) n1 = N_NODES;
    for (int n = n0; n < n1; ++n) {
        const float* row = h1 + (size_t)n * D1;
        float acc = 0.0f;
#pragma unroll
        for (int k = 0; k < D1; ++k) acc += row[k] * w[k];
        if (j < D2) p[(size_t)n * D2 + j] = acc;
    }
}

// ---------------- GEMM2: h2 = elu(h1 @ Ws + ns/deg_in + b2) ----------------
__global__ void gemm2_kernel(const float* __restrict__ h1, const float* __restrict__ ns,
                             const int* __restrict__ deg_in_cnt, const float* __restrict__ Ws,
                             const float* __restrict__ b2, float* __restrict__ h2) {
    int j = threadIdx.x;             // 0..127
    int jc = j < D2 ? j : D2 - 1;
    float w[D1];
#pragma unroll
    for (int k = 0; k < D1; ++k) w[k] = Ws[k * D2 + jc];
    float bias = b2[jc];
    int n0 = blockIdx.x * NPB;
    int n1 = n0 + NPB; if (n1 > N_NODES) n1 = N_NODES;
    for (int n = n0; n < n1; ++n) {
        const float* row = h1 + (size_t)n * D1;
        float acc = bias;
#pragma unroll
        for (int k = 0; k < D1; ++k) acc += row[k] * w[k];
        float inv = 1.0f / fmaxf((float)deg_in_cnt[n], 1.0f);
        float v = acc + ns[(size_t)n * D2 + jc] * inv;
        if (j < D2) h2[(size_t)n * D2 + j] = v > 0.0f ? v : expm1f(v);
    }
}

// ---------------- GEMM3: out = elu(h2 @ W3 + b3) ----------------
#define NPB3 32
__global__ void gemm3_kernel(const float* __restrict__ h2, const float* __restrict__ W3,
                             const float* __restrict__ b3, float* __restrict__ out) {
    int j = threadIdx.x;             // 0..63
    float w[D2];
#pragma unroll
    for (int k = 0; k < D2; ++k) w[k] = W3[k * D_OUT + j];
    float bias = b3[j];
    int n0 = blockIdx.x * NPB3;
    int n1 = n0 + NPB3; if (n1 > N_NODES) n1 = N_NODES;
    for (int n = n0; n < n1; ++n) {
        const float4* row = (const float4*)(h2 + (size_t)n * D2);
        float acc = bias;
#pragma unroll
        for (int k4 = 0; k4 < D2 / 4; ++k4) {
            float4 a = row[k4];
            acc += a.x * w[4 * k4 + 0];
            acc += a.y * w[4 * k4 + 1];
            acc += a.z * w[4 * k4 + 2];
            acc += a.w * w[4 * k4 + 3];
        }
        out[(size_t)n * D_OUT + j] = acc > 0.0f ? acc : expm1f(acc);
    }
}

extern "C" void kernel_launch(void* const* d_in, const int* in_sizes, int n_in,
                              void* d_out, int out_size, void* d_ws, size_t ws_size,
                              hipStream_t stream) {
    const float* x  = (const float*)d_in[0];
    const int* src  = (const int*)d_in[1];
    const int* dst  = (const int*)d_in[2];
    const float* W1 = (const float*)d_in[3];
    const float* b1 = (const float*)d_in[4];
    const float* Wn = (const float*)d_in[5];
    const float* Ws = (const float*)d_in[6];
    const float* b2 = (const float*)d_in[7];
    const float* W3 = (const float*)d_in[8];
    const float* b3 = (const float*)d_in[9];
    float* out = (float*)d_out;

    // workspace layout (elements of 4B):
    //  [0,50000)          deg_out_cnt (int)
    //  [50000,100000)     deg_in_cnt  (int)
    //  [100000,150004)    row_ptr     (int, 50001)
    //  [150004,200004)    cursor      (int)
    //  [200004,1000004)   edge_src    (int)
    //  [1000064, +6.4M)   xs    -> later ns (overlay; xs dead after gather_x)
    //  [7400064, +6.4M)   agg   -> later p -> later h2 (overlays; each dead in turn)
    //  [13800064, +7.5M)  h1
    //  total 21.3M elems = 85.2 MB
    char* wsb = (char*)d_ws;
    int*   deg_out_cnt = (int*)wsb;
    int*   deg_in_cnt  = deg_out_cnt + 50000;
    int*   row_ptr     = deg_out_cnt + 100000;
    int*   cursor      = deg_out_cnt + 150004;
    int*   edge_src    = deg_out_cnt + 200004;
    float* xs          = (float*)wsb + 1000064;
    float* agg         = xs + (size_t)N_NODES * D_IN;
    float* h1          = agg + (size_t)N_NODES * D_IN;
    float* ns          = xs;    // overlay: xs dead after gather_x
    float* p           = agg;   // overlay: agg dead after gemm1
    float* h2          = agg;   // overlay: p dead after gather_p

    hipMemsetAsync(deg_out_cnt, 0, 100000 * sizeof(int), stream);
    hipMemsetAsync(cursor, 0, 50000 * sizeof(int), stream);

    count_kernel<<<(N_EDGES + 255) / 256, 256, 0, stream>>>(src, dst, deg_out_cnt, deg_in_cnt);
    scan_kernel<<<1, 1024, 0, stream>>>(deg_in_cnt, row_ptr);
    fill_kernel<<<(N_EDGES + 255) / 256, 256, 0, stream>>>(src, dst, row_ptr, cursor, edge_src);
    prescale_kernel<<<(N_NODES * 32 + 255) / 256, 256, 0, stream>>>(x, deg_out_cnt, xs);
    gather_x<<<(N_NODES + 3) / 4, 256, 0, stream>>>(xs, row_ptr, edge_src, agg);
    gemm1_kernel<<<(N_NODES + NPB - 1) / NPB, 192, 0, stream>>>(agg, deg_in_cnt, W1, b1, h1);
    gemmP_kernel<<<(N_NODES + NPB - 1) / NPB, 128, 0, stream>>>(h1, Wn, p);
    gather_p<<<(N_NODES + 3) / 4, 256, 0, stream>>>(p, row_ptr, edge_src, ns);
    gemm2_kernel<<<(N_NODES + NPB - 1) / NPB, 128, 0, stream>>>(h1, ns, deg_in_cnt, Ws, b2, h2);
    gemm3_kernel<<<(N_NODES + NPB3 - 1) / NPB3, 64, 0, stream>>>(h2, W3, b3, out);
}

// Round 3
// 1090.858 us; speedup vs baseline: 3.7379x; 1.6485x over previous
//
#include <hip/hip_runtime.h>
#include <math.h>

#define N_NODES 50000
#define N_EDGES 800000
#define D_IN 128
#define D1 150
#define D2 100
#define D_OUT 64

// ---------------- degree counting (int atomics) ----------------
__global__ void count_kernel(const int* __restrict__ src, const int* __restrict__ dst,
                             int* __restrict__ deg_out_cnt, int* __restrict__ deg_in_cnt) {
    int e = blockIdx.x * blockDim.x + threadIdx.x;
    if (e < N_EDGES) {
        atomicAdd(&deg_out_cnt[src[e]], 1);
        atomicAdd(&deg_in_cnt[dst[e]], 1);
    }
}

// ---------------- exclusive scan of deg_in -> row_ptr (single block) ----------------
__global__ void scan_kernel(const int* __restrict__ cnt, int* __restrict__ row_ptr) {
    __shared__ int buf[1024];
    __shared__ int carry_s;
    int t = threadIdx.x;
    if (t == 0) carry_s = 0;
    __syncthreads();
    for (int base = 0; base < N_NODES; base += 1024) {
        int i = base + t;
        int v = (i < N_NODES) ? cnt[i] : 0;
        buf[t] = v;
        __syncthreads();
        for (int off = 1; off < 1024; off <<= 1) {
            int add = (t >= off) ? buf[t - off] : 0;
            __syncthreads();
            buf[t] += add;
            __syncthreads();
        }
        int carry = carry_s;
        if (i < N_NODES) row_ptr[i] = carry + buf[t] - v;   // exclusive
        int total = buf[1023];
        __syncthreads();
        if (t == 0) carry_s = carry + total;
        __syncthreads();
    }
    if (t == 0) row_ptr[N_NODES] = carry_s;
}

// ---------------- CSR fill: bucket edges by dst ----------------
__global__ void fill_kernel(const int* __restrict__ src, const int* __restrict__ dst,
                            const int* __restrict__ row_ptr, int* __restrict__ cursor,
                            int* __restrict__ edge_src) {
    int e = blockIdx.x * blockDim.x + threadIdx.x;
    if (e < N_EDGES) {
        int d = dst[e];
        int pos = atomicAdd(&cursor[d], 1);
        edge_src[row_ptr[d] + pos] = src[e];
    }
}

// ---------------- xs = x * norm_out ----------------
__global__ void prescale_kernel(const float* __restrict__ x, const int* __restrict__ deg_out_cnt,
                                float* __restrict__ xs) {
    int item = blockIdx.x * blockDim.x + threadIdx.x;   // N_NODES*32 float4 chunks
    if (item >= N_NODES * 32) return;
    int n = item >> 5;
    float no = rsqrtf(fmaxf((float)deg_out_cnt[n], 1.0f));
    float4 v = ((const float4*)x)[item];
    v.x *= no; v.y *= no; v.z *= no; v.w *= no;
    ((float4*)xs)[item] = v;
}

// ---------------- gather 1: agg[n] = sum_{e in in(n)} xs[src[e]] ----------------
// one wave per node; lane t holds floats t and t+64
__global__ void gather_x(const float* __restrict__ xs, const int* __restrict__ row_ptr,
                         const int* __restrict__ edge_src, float* __restrict__ agg) {
    int wave = threadIdx.x >> 6;
    int lane = threadIdx.x & 63;
    int n = blockIdx.x * 4 + wave;
    if (n >= N_NODES) return;
    int beg = row_ptr[n], end = row_ptr[n + 1];
    float a0 = 0.0f, a1 = 0.0f;
    for (int e = beg; e < end; ++e) {
        int s = edge_src[e];
        const float* r = xs + (size_t)s * D_IN;
        a0 += r[lane];
        a1 += r[lane + 64];
    }
    agg[(size_t)n * D_IN + lane] = a0;
    agg[(size_t)n * D_IN + lane + 64] = a1;
}

// ---------------- gather 2: ns[n] = sum_{e in in(n)} p[src[e]] ----------------
__global__ void gather_p(const float* __restrict__ p, const int* __restrict__ row_ptr,
                         const int* __restrict__ edge_src, float* __restrict__ ns) {
    int wave = threadIdx.x >> 6;
    int lane = threadIdx.x & 63;
    int n = blockIdx.x * 4 + wave;
    if (n >= N_NODES) return;
    int beg = row_ptr[n], end = row_ptr[n + 1];
    float a0 = 0.0f, a1 = 0.0f;
    for (int e = beg; e < end; ++e) {
        int s = edge_src[e];
        const float* r = p + (size_t)s * D2;
        a0 += r[lane];
        if (lane < D2 - 64) a1 += r[lane + 64];
    }
    ns[(size_t)n * D2 + lane] = a0;
    if (lane < D2 - 64) ns[(size_t)n * D2 + lane + 64] = a1;
}

// ---------------- GEMM1: h1 = elu(norm_in * (agg @ W1) + b1) ----------------
// __launch_bounds__(192,2): VGPR cap 256 so w[128] stays in registers (R2: cap
// was 64 -> spill to scratch -> 1.3 GB HBM fetch in the sibling gemm2 kernel)
#define NPB 32
__global__ __launch_bounds__(192, 2)
void gemm1_kernel(const float* __restrict__ agg, const int* __restrict__ deg_in_cnt,
                  const float* __restrict__ W1, const float* __restrict__ b1,
                  float* __restrict__ h1) {
    int j = threadIdx.x;             // 0..191
    int jc = j < D1 ? j : D1 - 1;
    float w[D_IN];
#pragma unroll
    for (int k = 0; k < D_IN; ++k) w[k] = W1[k * D1 + jc];
    float bias = b1[jc];
    int n0 = blockIdx.x * NPB;
    int n1 = n0 + NPB; if (n1 > N_NODES) n1 = N_NODES;
    for (int n = n0; n < n1; ++n) {
        const float4* arow = (const float4*)(agg + (size_t)n * D_IN);
        float acc = 0.0f;
#pragma unroll
        for (int k4 = 0; k4 < D_IN / 4; ++k4) {
            float4 a = arow[k4];
            acc += a.x * w[4 * k4 + 0];
            acc += a.y * w[4 * k4 + 1];
            acc += a.z * w[4 * k4 + 2];
            acc += a.w * w[4 * k4 + 3];
        }
        if (j < D1) {
            float ni = rsqrtf(fmaxf((float)deg_in_cnt[n], 1.0f));
            float v = acc * ni + bias;
            h1[(size_t)n * D1 + j] = v > 0.0f ? v : expm1f(v);
        }
    }
}

// ---------------- GEMM-P: p = h1 @ Wn ----------------
__global__ __launch_bounds__(128, 2)
void gemmP_kernel(const float* __restrict__ h1, const float* __restrict__ Wn,
                  float* __restrict__ p) {
    int j = threadIdx.x;             // 0..127
    int jc = j < D2 ? j : D2 - 1;
    float w[D1];
#pragma unroll
    for (int k = 0; k < D1; ++k) w[k] = Wn[k * D2 + jc];
    int n0 = blockIdx.x * NPB;
    int n1 = n0 + NPB; if (n1 > N_NODES) n1 = N_NODES;
    for (int n = n0; n < n1; ++n) {
        const float* row = h1 + (size_t)n * D1;
        float acc = 0.0f;
#pragma unroll
        for (int k = 0; k < D1; ++k) acc += row[k] * w[k];
        if (j < D2) p[(size_t)n * D2 + j] = acc;
    }
}

// ---------------- GEMM2: h2 = elu(h1 @ Ws + ns/deg_in + b2) ----------------
__global__ __launch_bounds__(128, 2)
void gemm2_kernel(const float* __restrict__ h1, const float* __restrict__ ns,
                  const int* __restrict__ deg_in_cnt, const float* __restrict__ Ws,
                  const float* __restrict__ b2, float* __restrict__ h2) {
    int j = threadIdx.x;             // 0..127
    int jc = j < D2 ? j : D2 - 1;
    float w[D1];
#pragma unroll
    for (int k = 0; k < D1; ++k) w[k] = Ws[k * D2 + jc];
    float bias = b2[jc];
    int n0 = blockIdx.x * NPB;
    int n1 = n0 + NPB; if (n1 > N_NODES) n1 = N_NODES;
    for (int n = n0; n < n1; ++n) {
        const float* row = h1 + (size_t)n * D1;
        float acc = bias;
#pragma unroll
        for (int k = 0; k < D1; ++k) acc += row[k] * w[k];
        float inv = 1.0f / fmaxf((float)deg_in_cnt[n], 1.0f);
        float v = acc + ns[(size_t)n * D2 + jc] * inv;
        if (j < D2) h2[(size_t)n * D2 + j] = v > 0.0f ? v : expm1f(v);
    }
}

// ---------------- GEMM3: out = elu(h2 @ W3 + b3) ----------------
#define NPB3 32
__global__ __launch_bounds__(64, 2)
void gemm3_kernel(const float* __restrict__ h2, const float* __restrict__ W3,
                  const float* __restrict__ b3, float* __restrict__ out) {
    int j = threadIdx.x;             // 0..63
    float w[D2];
#pragma unroll
    for (int k = 0; k < D2; ++k) w[k] = W3[k * D_OUT + j];
    float bias = b3[j];
    int n0 = blockIdx.x * NPB3;
    int n1 = n0 + NPB3; if (n1 > N_NODES) n1 = N_NODES;
    for (int n = n0; n < n1; ++n) {
        const float4* row = (const float4*)(h2 + (size_t)n * D2);
        float acc = bias;
#pragma unroll
        for (int k4 = 0; k4 < D2 / 4; ++k4) {
            float4 a = row[k4];
            acc += a.x * w[4 * k4 + 0];
            acc += a.y * w[4 * k4 + 1];
            acc += a.z * w[4 * k4 + 2];
            acc += a.w * w[4 * k4 + 3];
        }
        out[(size_t)n * D_OUT + j] = acc > 0.0f ? acc : expm1f(acc);
    }
}

extern "C" void kernel_launch(void* const* d_in, const int* in_sizes, int n_in,
                              void* d_out, int out_size, void* d_ws, size_t ws_size,
                              hipStream_t stream) {
    const float* x  = (const float*)d_in[0];
    const int* src  = (const int*)d_in[1];
    const int* dst  = (const int*)d_in[2];
    const float* W1 = (const float*)d_in[3];
    const float* b1 = (const float*)d_in[4];
    const float* Wn = (const float*)d_in[5];
    const float* Ws = (const float*)d_in[6];
    const float* b2 = (const float*)d_in[7];
    const float* W3 = (const float*)d_in[8];
    const float* b3 = (const float*)d_in[9];
    float* out = (float*)d_out;

    // workspace layout (elements of 4B):
    //  [0,50000)          deg_out_cnt (int)
    //  [50000,100000)     deg_in_cnt  (int)
    //  [100000,150004)    row_ptr     (int, 50001)
    //  [150004,200004)    cursor      (int)
    //  [200004,1000004)   edge_src    (int)
    //  [1000064, +6.4M)   xs    -> later ns (overlay; xs dead after gather_x)
    //  [7400064, +6.4M)   agg   -> later p -> later h2 (overlays; each dead in turn)
    //  [13800064, +7.5M)  h1
    //  total 21.3M elems = 85.2 MB
    char* wsb = (char*)d_ws;
    int*   deg_out_cnt = (int*)wsb;
    int*   deg_in_cnt  = deg_out_cnt + 50000;
    int*   row_ptr     = deg_out_cnt + 100000;
    int*   cursor      = deg_out_cnt + 150004;
    int*   edge_src    = deg_out_cnt + 200004;
    float* xs          = (float*)wsb + 1000064;
    float* agg         = xs + (size_t)N_NODES * D_IN;
    float* h1          = agg + (size_t)N_NODES * D_IN;
    float* ns          = xs;    // overlay: xs dead after gather_x
    float* p           = agg;   // overlay: agg dead after gemm1
    float* h2          = agg;   // overlay: p dead after gather_p

    hipMemsetAsync(deg_out_cnt, 0, 100000 * sizeof(int), stream);
    hipMemsetAsync(cursor, 0, 50000 * sizeof(int), stream);

    count_kernel<<<(N_EDGES + 255) / 256, 256, 0, stream>>>(src, dst, deg_out_cnt, deg_in_cnt);
    scan_kernel<<<1, 1024, 0, stream>>>(deg_in_cnt, row_ptr);
    fill_kernel<<<(N_EDGES + 255) / 256, 256, 0, stream>>>(src, dst, row_ptr, cursor, edge_src);
    prescale_kernel<<<(N_NODES * 32 + 255) / 256, 256, 0, stream>>>(x, deg_out_cnt, xs);
    gather_x<<<(N_NODES + 3) / 4, 256, 0, stream>>>(xs, row_ptr, edge_src, agg);
    gemm1_kernel<<<(N_NODES + NPB - 1) / NPB, 192, 0, stream>>>(agg, deg_in_cnt, W1, b1, h1);
    gemmP_kernel<<<(N_NODES + NPB - 1) / NPB, 128, 0, stream>>>(h1, Wn, p);
    gather_p<<<(N_NODES + 3) / 4, 256, 0, stream>>>(p, row_ptr, edge_src, ns);
    gemm2_kernel<<<(N_NODES + NPB - 1) / NPB, 128, 0, stream>>>(h1, ns, deg_in_cnt, Ws, b2, h2);
    gemm3_kernel<<<(N_NODES + NPB3 - 1) / NPB3, 64, 0, stream>>>(h2, W3, b3, out);
}

// Round 4
// 653.028 us; speedup vs baseline: 6.2440x; 1.6705x over previous
//
#include <hip/hip_runtime.h>
#include <math.h>

#define N_NODES 50000
#define N_EDGES 800000
#define D_IN 128
#define D1 150
#define LD1 152   // h1 leading dim padded for 16B alignment
#define D2 100
#define D_OUT 64

__device__ __forceinline__ float elu(float v) { return v > 0.0f ? v : expm1f(v); }

// ---------------- degree counting (int atomics) ----------------
__global__ void count_kernel(const int* __restrict__ src, const int* __restrict__ dst,
                             int* __restrict__ deg_out_cnt, int* __restrict__ deg_in_cnt) {
    int e = blockIdx.x * blockDim.x + threadIdx.x;
    if (e < N_EDGES) {
        atomicAdd(&deg_out_cnt[src[e]], 1);
        atomicAdd(&deg_in_cnt[dst[e]], 1);
    }
}

// ---------------- exclusive scan of deg_in -> row_ptr (single block) ----------------
__global__ void scan_kernel(const int* __restrict__ cnt, int* __restrict__ row_ptr) {
    __shared__ int buf[1024];
    __shared__ int carry_s;
    int t = threadIdx.x;
    if (t == 0) carry_s = 0;
    __syncthreads();
    for (int base = 0; base < N_NODES; base += 1024) {
        int i = base + t;
        int v = (i < N_NODES) ? cnt[i] : 0;
        buf[t] = v;
        __syncthreads();
        for (int off = 1; off < 1024; off <<= 1) {
            int add = (t >= off) ? buf[t - off] : 0;
            __syncthreads();
            buf[t] += add;
            __syncthreads();
        }
        int carry = carry_s;
        if (i < N_NODES) row_ptr[i] = carry + buf[t] - v;   // exclusive
        int total = buf[1023];
        __syncthreads();
        if (t == 0) carry_s = carry + total;
        __syncthreads();
    }
    if (t == 0) row_ptr[N_NODES] = carry_s;
}

// ---------------- CSR fill: bucket edges by dst ----------------
__global__ void fill_kernel(const int* __restrict__ src, const int* __restrict__ dst,
                            const int* __restrict__ row_ptr, int* __restrict__ cursor,
                            int* __restrict__ edge_src) {
    int e = blockIdx.x * blockDim.x + threadIdx.x;
    if (e < N_EDGES) {
        int d = dst[e];
        int pos = atomicAdd(&cursor[d], 1);
        edge_src[row_ptr[d] + pos] = src[e];
    }
}

// ---------------- xs = x * norm_out ----------------
__global__ void prescale_kernel(const float* __restrict__ x, const int* __restrict__ deg_out_cnt,
                                float* __restrict__ xs) {
    int item = blockIdx.x * blockDim.x + threadIdx.x;   // N_NODES*32 float4 chunks
    if (item >= N_NODES * 32) return;
    int n = item >> 5;
    float no = rsqrtf(fmaxf((float)deg_out_cnt[n], 1.0f));
    float4 v = ((const float4*)x)[item];
    v.x *= no; v.y *= no; v.z *= no; v.w *= no;
    ((float4*)xs)[item] = v;
}

// ---------------- gather 1: agg[n] = sum_{e in in(n)} xs[src[e]] ----------------
__global__ void gather_x(const float* __restrict__ xs, const int* __restrict__ row_ptr,
                         const int* __restrict__ edge_src, float* __restrict__ agg) {
    int wave = threadIdx.x >> 6;
    int lane = threadIdx.x & 63;
    int n = blockIdx.x * 4 + wave;
    if (n >= N_NODES) return;
    int beg = row_ptr[n], end = row_ptr[n + 1];
    float a0 = 0.0f, a1 = 0.0f;
    for (int e = beg; e < end; ++e) {
        int s = edge_src[e];
        const float* r = xs + (size_t)s * D_IN;
        a0 += r[lane];
        a1 += r[lane + 64];
    }
    agg[(size_t)n * D_IN + lane] = a0;
    agg[(size_t)n * D_IN + lane + 64] = a1;
}

// ---------------- gather 2: ns[n] = sum_{e in in(n)} p[src[e]] ----------------
__global__ void gather_p(const float* __restrict__ p, const int* __restrict__ row_ptr,
                         const int* __restrict__ edge_src, float* __restrict__ ns) {
    int wave = threadIdx.x >> 6;
    int lane = threadIdx.x & 63;
    int n = blockIdx.x * 4 + wave;
    if (n >= N_NODES) return;
    int beg = row_ptr[n], end = row_ptr[n + 1];
    float a0 = 0.0f, a1 = 0.0f;
    for (int e = beg; e < end; ++e) {
        int s = edge_src[e];
        const float* r = p + (size_t)s * D2;
        a0 += r[lane];
        if (lane < D2 - 64) a1 += r[lane + 64];
    }
    ns[(size_t)n * D2 + lane] = a0;
    if (lane < D2 - 64) ns[(size_t)n * D2 + lane + 64] = a1;
}

// ================= tiled fp32 GEMM: C = epi(A[M x K] @ W[K x N]) =================
// BM=128, BN=64, BK=16; 256 threads as 16x16; thread tile TM=8 x TN=4.
// A staged TRANSPOSED in LDS so inner loop is 3x ds_read_b128 + 32 indep FMAs.
// No per-thread register arrays -> no spill (R3 lesson: w[150] spilled at VGPR=128).
#define BM 128
#define BN 64
#define BK 16
#define TM 8
#define TN 4

// EPI: 0 = none (p), 1 = elu(acc*rsqrt(deg)+bias) (h1), 2 = elu(acc+bias+extra*inv_deg) (h2),
//      3 = elu(acc+bias) (out)
template <int K, int KP, int N, int LDA, int LDC, int EPI>
__global__ __launch_bounds__(256, 2)
void gemm_tiled(const float* __restrict__ A, const float* __restrict__ W,
                const float* __restrict__ bias, const float* __restrict__ extra,
                const int* __restrict__ deg_in_cnt, float* __restrict__ C) {
    __shared__ __align__(16) float AsT[BK][BM + 4];  // stride 132 floats (528B, 16B-aligned)
    __shared__ __align__(16) float Bs[BK][BN + 4];   // stride 68 floats (272B, 16B-aligned)

    const int tid = threadIdx.x;
    const int tx = tid & 15;       // col group
    const int ty = tid >> 4;       // row group
    const int m0 = blockIdx.x * BM;
    const int n0 = blockIdx.y * BN;

    float acc[TM][TN];
#pragma unroll
    for (int i = 0; i < TM; ++i)
#pragma unroll
        for (int j = 0; j < TN; ++j) acc[i][j] = 0.0f;

    const int arow = tid >> 1;            // 0..127 (row within A tile)
    const int af = (tid & 1) * 2;         // float4-column base: 0 or 2
    const int grow = m0 + arow;
    const int wrow = tid >> 4;            // 0..15 (k within W tile)
    const int wcol = (tid & 15) * 4;      // col within W tile

    for (int k0 = 0; k0 < KP; k0 += BK) {
        __syncthreads();
        // ---- stage A (transposed) ----
        if (grow < N_NODES && k0 + BK <= K) {
            const float* ap = A + (size_t)grow * LDA + k0 + af * 4;
            float4 v0 = *(const float4*)(ap);
            float4 v1 = *(const float4*)(ap + 4);
            AsT[af * 4 + 0][arow] = v0.x;
            AsT[af * 4 + 1][arow] = v0.y;
            AsT[af * 4 + 2][arow] = v0.z;
            AsT[af * 4 + 3][arow] = v0.w;
            AsT[af * 4 + 4][arow] = v1.x;
            AsT[af * 4 + 5][arow] = v1.y;
            AsT[af * 4 + 6][arow] = v1.z;
            AsT[af * 4 + 7][arow] = v1.w;
        } else {
#pragma unroll
            for (int i = 0; i < 8; ++i) {
                int k = k0 + af * 4 + i;
                AsT[af * 4 + i][arow] =
                    (grow < N_NODES && k < K) ? A[(size_t)grow * LDA + k] : 0.0f;
            }
        }
        // ---- stage W ----
#pragma unroll
        for (int j = 0; j < 4; ++j) {
            int k = k0 + wrow;
            int n = n0 + wcol + j;
            Bs[wrow][wcol + j] = (k < K && n < N) ? W[(size_t)k * N + n] : 0.0f;
        }
        __syncthreads();
        // ---- inner product ----
#pragma unroll
        for (int kk = 0; kk < BK; ++kk) {
            float4 a0 = *(const float4*)&AsT[kk][ty * TM];
            float4 a1 = *(const float4*)&AsT[kk][ty * TM + 4];
            float4 b = *(const float4*)&Bs[kk][tx * TN];
            float av[TM] = {a0.x, a0.y, a0.z, a0.w, a1.x, a1.y, a1.z, a1.w};
            float bv[TN] = {b.x, b.y, b.z, b.w};
#pragma unroll
            for (int i = 0; i < TM; ++i)
#pragma unroll
                for (int j = 0; j < TN; ++j) acc[i][j] += av[i] * bv[j];
        }
    }

    // ---- epilogue ----
#pragma unroll
    for (int i = 0; i < TM; ++i) {
        int row = m0 + ty * TM + i;
        if (row >= N_NODES) continue;
        float rmul = 1.0f, rinv = 1.0f;
        if (EPI == 1) rmul = rsqrtf(fmaxf((float)deg_in_cnt[row], 1.0f));
        if (EPI == 2) rinv = 1.0f / fmaxf((float)deg_in_cnt[row], 1.0f);
#pragma unroll
        for (int j = 0; j < TN; ++j) {
            int col = n0 + tx * TN + j;
            if (col >= N) continue;
            float v = acc[i][j];
            if (EPI == 1) v = elu(v * rmul + bias[col]);
            else if (EPI == 2) v = elu(v + bias[col] + extra[(size_t)row * D2 + col] * rinv);
            else if (EPI == 3) v = elu(v + bias[col]);
            C[(size_t)row * LDC + col] = v;
        }
    }
}

extern "C" void kernel_launch(void* const* d_in, const int* in_sizes, int n_in,
                              void* d_out, int out_size, void* d_ws, size_t ws_size,
                              hipStream_t stream) {
    const float* x  = (const float*)d_in[0];
    const int* src  = (const int*)d_in[1];
    const int* dst  = (const int*)d_in[2];
    const float* W1 = (const float*)d_in[3];
    const float* b1 = (const float*)d_in[4];
    const float* Wn = (const float*)d_in[5];
    const float* Ws = (const float*)d_in[6];
    const float* b2 = (const float*)d_in[7];
    const float* W3 = (const float*)d_in[8];
    const float* b3 = (const float*)d_in[9];
    float* out = (float*)d_out;

    // workspace layout (4B elements):
    //  [0,50000)          deg_out_cnt (int)
    //  [50000,100000)     deg_in_cnt  (int)
    //  [100000,150004)    row_ptr     (int, 50001)
    //  [150004,200004)    cursor      (int)
    //  [200004,1000004)   edge_src    (int)
    //  [1000064, +6.4M)   xs    -> later ns (overlay)
    //  [7400064, +6.4M)   agg   -> later p -> later h2 (overlays)
    //  [13800064, +7.6M)  h1 (ld 152)
    //  total 21.4M elems = 85.6 MB
    char* wsb = (char*)d_ws;
    int*   deg_out_cnt = (int*)wsb;
    int*   deg_in_cnt  = deg_out_cnt + 50000;
    int*   row_ptr     = deg_out_cnt + 100000;
    int*   cursor      = deg_out_cnt + 150004;
    int*   edge_src    = deg_out_cnt + 200004;
    float* xs          = (float*)wsb + 1000064;
    float* agg         = xs + (size_t)N_NODES * D_IN;
    float* h1          = agg + (size_t)N_NODES * D_IN;
    float* ns          = xs;    // overlay: xs dead after gather_x
    float* p           = agg;   // overlay: agg dead after gemm1
    float* h2          = agg;   // overlay: p dead after gather_p

    hipMemsetAsync(deg_out_cnt, 0, 100000 * sizeof(int), stream);
    hipMemsetAsync(cursor, 0, 50000 * sizeof(int), stream);

    count_kernel<<<(N_EDGES + 255) / 256, 256, 0, stream>>>(src, dst, deg_out_cnt, deg_in_cnt);
    scan_kernel<<<1, 1024, 0, stream>>>(deg_in_cnt, row_ptr);
    fill_kernel<<<(N_EDGES + 255) / 256, 256, 0, stream>>>(src, dst, row_ptr, cursor, edge_src);
    prescale_kernel<<<(N_NODES * 32 + 255) / 256, 256, 0, stream>>>(x, deg_out_cnt, xs);
    gather_x<<<(N_NODES + 3) / 4, 256, 0, stream>>>(xs, row_ptr, edge_src, agg);

    const int MB = (N_NODES + BM - 1) / BM;   // 391
    // gemm1: h1 = elu(norm_in * (agg @ W1) + b1)   [K=128, N=150]
    gemm_tiled<128, 128, 150, 128, LD1, 1>
        <<<dim3(MB, (150 + BN - 1) / BN), 256, 0, stream>>>(agg, W1, b1, nullptr, deg_in_cnt, h1);
    // gemmP: p = h1 @ Wn                            [K=150, N=100]
    gemm_tiled<150, 160, 100, LD1, 100, 0>
        <<<dim3(MB, (100 + BN - 1) / BN), 256, 0, stream>>>(h1, Wn, nullptr, nullptr, nullptr, p);
    gather_p<<<(N_NODES + 3) / 4, 256, 0, stream>>>(p, row_ptr, edge_src, ns);
    // gemm2: h2 = elu(h1 @ Ws + b2 + ns/deg)        [K=150, N=100]
    gemm_tiled<150, 160, 100, LD1, 100, 2>
        <<<dim3(MB, (100 + BN - 1) / BN), 256, 0, stream>>>(h1, Ws, b2, ns, deg_in_cnt, h2);
    // gemm3: out = elu(h2 @ W3 + b3)                [K=100, N=64]
    gemm_tiled<100, 112, 64, 100, 64, 3>
        <<<dim3(MB, 1), 256, 0, stream>>>(h2, W3, b3, nullptr, nullptr, out);
}

// Round 5
// 505.556 us; speedup vs baseline: 8.0654x; 1.2917x over previous
//
#include <hip/hip_runtime.h>
#include <math.h>

#define N_NODES 50000
#define N_EDGES 800000
#define D_IN 128
#define D1 150
#define LD1 152   // h1 leading dim padded for 16B alignment
#define D2 100
#define LDP 128   // p / ns leading dim padded so gathers use full-row float4 half-waves
#define D_OUT 64

__device__ __forceinline__ float elu(float v) { return v > 0.0f ? v : expm1f(v); }

// ---------------- degree counting (int atomics) ----------------
__global__ void count_kernel(const int* __restrict__ src, const int* __restrict__ dst,
                             int* __restrict__ deg_out_cnt, int* __restrict__ deg_in_cnt) {
    int e = blockIdx.x * blockDim.x + threadIdx.x;
    if (e < N_EDGES) {
        atomicAdd(&deg_out_cnt[src[e]], 1);
        atomicAdd(&deg_in_cnt[dst[e]], 1);
    }
}

// ---------------- hierarchical exclusive scan (R4: replaces 90us single-block scan) ----
#define SCAN_TILE 1024
#define N_SBLK ((N_NODES + SCAN_TILE - 1) / SCAN_TILE)   // 49

__global__ __launch_bounds__(256) void scan1_kernel(const int* __restrict__ cnt,
                                                    int* __restrict__ excl,
                                                    int* __restrict__ bsum) {
    int t = threadIdx.x, b = blockIdx.x;
    int base = b * SCAN_TILE + t * 4;
    int v0 = base + 0 < N_NODES ? cnt[base + 0] : 0;
    int v1 = base + 1 < N_NODES ? cnt[base + 1] : 0;
    int v2 = base + 2 < N_NODES ? cnt[base + 2] : 0;
    int v3 = base + 3 < N_NODES ? cnt[base + 3] : 0;
    int s = v0 + v1 + v2 + v3;
    int lane = t & 63, wv = t >> 6;
    int inc = s;
#pragma unroll
    for (int off = 1; off < 64; off <<= 1) {
        int y = __shfl_up(inc, off);
        if (lane >= off) inc += y;
    }
    __shared__ int wsum[4];
    if (lane == 63) wsum[wv] = inc;
    __syncthreads();
    int woff = 0;
    for (int w = 0; w < wv; ++w) woff += wsum[w];
    int ex = woff + inc - s;
    if (base + 0 < N_NODES) excl[base + 0] = ex;
    if (base + 1 < N_NODES) excl[base + 1] = ex + v0;
    if (base + 2 < N_NODES) excl[base + 2] = ex + v0 + v1;
    if (base + 3 < N_NODES) excl[base + 3] = ex + v0 + v1 + v2;
    if (t == 255) bsum[b] = woff + inc;
}

__global__ void scan2_kernel(int* __restrict__ bsum) {
    int lane = threadIdx.x;           // 64 threads, N_SBLK=49 fits one wave
    int v = lane < N_SBLK ? bsum[lane] : 0;
    int inc = v;
#pragma unroll
    for (int off = 1; off < 64; off <<= 1) {
        int y = __shfl_up(inc, off);
        if (lane >= off) inc += y;
    }
    if (lane < N_SBLK) bsum[lane] = inc - v;   // exclusive
}

__global__ void scan3_kernel(const int* __restrict__ excl, const int* __restrict__ bsum,
                             int* __restrict__ row_ptr) {
    int i = blockIdx.x * blockDim.x + threadIdx.x;
    if (i < N_NODES) row_ptr[i] = excl[i] + bsum[i >> 10];
    if (i == 0) row_ptr[N_NODES] = N_EDGES;   // total degree is a known constant
}

// ---------------- CSR fill: bucket edges by dst ----------------
__global__ void fill_kernel(const int* __restrict__ src, const int* __restrict__ dst,
                            const int* __restrict__ row_ptr, int* __restrict__ cursor,
                            int* __restrict__ edge_src) {
    int e = blockIdx.x * blockDim.x + threadIdx.x;
    if (e < N_EDGES) {
        int d = dst[e];
        int pos = atomicAdd(&cursor[d], 1);
        edge_src[row_ptr[d] + pos] = src[e];
    }
}

// ---------------- xs = x * norm_out ----------------
__global__ void prescale_kernel(const float* __restrict__ x, const int* __restrict__ deg_out_cnt,
                                float* __restrict__ xs) {
    int item = blockIdx.x * blockDim.x + threadIdx.x;   // N_NODES*32 float4 chunks
    if (item >= N_NODES * 32) return;
    int n = item >> 5;
    float no = rsqrtf(fmaxf((float)deg_out_cnt[n], 1.0f));
    float4 v = ((const float4*)x)[item];
    v.x *= no; v.y *= no; v.z *= no; v.w *= no;
    ((float4*)xs)[item] = v;
}

// ---------------- gather 1: agg[n] = sum_{e in in(n)} xs[src[e]] ----------------
// one wave per node; half-wave (32 lanes x float4 = 128 floats) covers a full row;
// 2 edges per iteration + 2x unroll for MLP; cross-half shfl_xor reduce at end.
__global__ __launch_bounds__(256) void gather_x(const float* __restrict__ xs,
                                                const int* __restrict__ row_ptr,
                                                const int* __restrict__ edge_src,
                                                float* __restrict__ agg) {
    int wave = threadIdx.x >> 6;
    int lane = threadIdx.x & 63;
    int half = lane >> 5;
    int c = lane & 31;                 // float4 index within row
    int n = blockIdx.x * 4 + wave;
    if (n >= N_NODES) return;
    int beg = row_ptr[n], end = row_ptr[n + 1];
    float4 acc = {0.0f, 0.0f, 0.0f, 0.0f};
    int e = beg + half;
    for (; e + 2 < end; e += 4) {
        int s0 = edge_src[e];
        int s1 = edge_src[e + 2];
        float4 v0 = ((const float4*)(xs + (size_t)s0 * D_IN))[c];
        float4 v1 = ((const float4*)(xs + (size_t)s1 * D_IN))[c];
        acc.x += v0.x + v1.x;
        acc.y += v0.y + v1.y;
        acc.z += v0.z + v1.z;
        acc.w += v0.w + v1.w;
    }
    if (e < end) {
        int s = edge_src[e];
        float4 v = ((const float4*)(xs + (size_t)s * D_IN))[c];
        acc.x += v.x; acc.y += v.y; acc.z += v.z; acc.w += v.w;
    }
    acc.x += __shfl_xor(acc.x, 32);
    acc.y += __shfl_xor(acc.y, 32);
    acc.z += __shfl_xor(acc.z, 32);
    acc.w += __shfl_xor(acc.w, 32);
    if (half == 0) ((float4*)(agg + (size_t)n * D_IN))[c] = acc;
}

// ---------------- gather 2: ns[n] = sum_{e in in(n)} p[src[e]]  (rows padded to 128) ----
__global__ __launch_bounds__(256) void gather_p(const float* __restrict__ p,
                                                const int* __restrict__ row_ptr,
                                                const int* __restrict__ edge_src,
                                                float* __restrict__ ns) {
    int wave = threadIdx.x >> 6;
    int lane = threadIdx.x & 63;
    int half = lane >> 5;
    int c = lane & 31;
    int n = blockIdx.x * 4 + wave;
    if (n >= N_NODES) return;
    int beg = row_ptr[n], end = row_ptr[n + 1];
    float4 acc = {0.0f, 0.0f, 0.0f, 0.0f};
    int e = beg + half;
    for (; e + 2 < end; e += 4) {
        int s0 = edge_src[e];
        int s1 = edge_src[e + 2];
        float4 v0 = ((const float4*)(p + (size_t)s0 * LDP))[c];
        float4 v1 = ((const float4*)(p + (size_t)s1 * LDP))[c];
        acc.x += v0.x + v1.x;
        acc.y += v0.y + v1.y;
        acc.z += v0.z + v1.z;
        acc.w += v0.w + v1.w;
    }
    if (e < end) {
        int s = edge_src[e];
        float4 v = ((const float4*)(p + (size_t)s * LDP))[c];
        acc.x += v.x; acc.y += v.y; acc.z += v.z; acc.w += v.w;
    }
    acc.x += __shfl_xor(acc.x, 32);
    acc.y += __shfl_xor(acc.y, 32);
    acc.z += __shfl_xor(acc.z, 32);
    acc.w += __shfl_xor(acc.w, 32);
    if (half == 0) ((float4*)(ns + (size_t)n * LDP))[c] = acc;
}

// ================= tiled fp32 GEMM: C = epi(A[M x K] @ W[K x N]) =================
// BM=128, BN=64, BK=16; 256 threads as 16x16; thread tile TM=8 x TN=4.
// Epilogue writes 0 for cols in [N, LDC) covered by the grid (pads p for gather_p).
#define BM 128
#define BN 64
#define BK 16
#define TM 8
#define TN 4

// EPI: 0 = none, 1 = elu(acc*rsqrt(deg)+bias), 2 = elu(acc+bias+extra*inv_deg), 3 = elu(acc+bias)
template <int K, int KP, int N, int LDA, int LDC, int EPI>
__global__ __launch_bounds__(256, 2)
void gemm_tiled(const float* __restrict__ A, const float* __restrict__ W,
                const float* __restrict__ bias, const float* __restrict__ extra,
                const int* __restrict__ deg_in_cnt, float* __restrict__ C) {
    __shared__ __align__(16) float AsT[BK][BM + 4];
    __shared__ __align__(16) float Bs[BK][BN + 4];

    const int tid = threadIdx.x;
    const int tx = tid & 15;
    const int ty = tid >> 4;
    const int m0 = blockIdx.x * BM;
    const int n0 = blockIdx.y * BN;

    float acc[TM][TN];
#pragma unroll
    for (int i = 0; i < TM; ++i)
#pragma unroll
        for (int j = 0; j < TN; ++j) acc[i][j] = 0.0f;

    const int arow = tid >> 1;
    const int af = (tid & 1) * 2;
    const int grow = m0 + arow;
    const int wrow = tid >> 4;
    const int wcol = (tid & 15) * 4;

    for (int k0 = 0; k0 < KP; k0 += BK) {
        __syncthreads();
        if (grow < N_NODES && k0 + BK <= K) {
            const float* ap = A + (size_t)grow * LDA + k0 + af * 4;
            float4 v0 = *(const float4*)(ap);
            float4 v1 = *(const float4*)(ap + 4);
            AsT[af * 4 + 0][arow] = v0.x;
            AsT[af * 4 + 1][arow] = v0.y;
            AsT[af * 4 + 2][arow] = v0.z;
            AsT[af * 4 + 3][arow] = v0.w;
            AsT[af * 4 + 4][arow] = v1.x;
            AsT[af * 4 + 5][arow] = v1.y;
            AsT[af * 4 + 6][arow] = v1.z;
            AsT[af * 4 + 7][arow] = v1.w;
        } else {
#pragma unroll
            for (int i = 0; i < 8; ++i) {
                int k = k0 + af * 4 + i;
                AsT[af * 4 + i][arow] =
                    (grow < N_NODES && k < K) ? A[(size_t)grow * LDA + k] : 0.0f;
            }
        }
#pragma unroll
        for (int j = 0; j < 4; ++j) {
            int k = k0 + wrow;
            int n = n0 + wcol + j;
            Bs[wrow][wcol + j] = (k < K && n < N) ? W[(size_t)k * N + n] : 0.0f;
        }
        __syncthreads();
#pragma unroll
        for (int kk = 0; kk < BK; ++kk) {
            float4 a0 = *(const float4*)&AsT[kk][ty * TM];
            float4 a1 = *(const float4*)&AsT[kk][ty * TM + 4];
            float4 b = *(const float4*)&Bs[kk][tx * TN];
            float av[TM] = {a0.x, a0.y, a0.z, a0.w, a1.x, a1.y, a1.z, a1.w};
            float bv[TN] = {b.x, b.y, b.z, b.w};
#pragma unroll
            for (int i = 0; i < TM; ++i)
#pragma unroll
                for (int j = 0; j < TN; ++j) acc[i][j] += av[i] * bv[j];
        }
    }

#pragma unroll
    for (int i = 0; i < TM; ++i) {
        int row = m0 + ty * TM + i;
        if (row >= N_NODES) continue;
        float rmul = 1.0f, rinv = 1.0f;
        if (EPI == 1) rmul = rsqrtf(fmaxf((float)deg_in_cnt[row], 1.0f));
        if (EPI == 2) rinv = 1.0f / fmaxf((float)deg_in_cnt[row], 1.0f);
#pragma unroll
        for (int j = 0; j < TN; ++j) {
            int col = n0 + tx * TN + j;
            if (col >= LDC) continue;
            float v = 0.0f;
            if (col < N) {
                v = acc[i][j];
                if (EPI == 1) v = elu(v * rmul + bias[col]);
                else if (EPI == 2) v = elu(v + bias[col] + extra[(size_t)row * LDP + col] * rinv);
                else if (EPI == 3) v = elu(v + bias[col]);
            }
            C[(size_t)row * LDC + col] = v;   // col in [N,LDC) -> zero pad
        }
    }
}

extern "C" void kernel_launch(void* const* d_in, const int* in_sizes, int n_in,
                              void* d_out, int out_size, void* d_ws, size_t ws_size,
                              hipStream_t stream) {
    const float* x  = (const float*)d_in[0];
    const int* src  = (const int*)d_in[1];
    const int* dst  = (const int*)d_in[2];
    const float* W1 = (const float*)d_in[3];
    const float* b1 = (const float*)d_in[4];
    const float* Wn = (const float*)d_in[5];
    const float* Ws = (const float*)d_in[6];
    const float* b2 = (const float*)d_in[7];
    const float* W3 = (const float*)d_in[8];
    const float* b3 = (const float*)d_in[9];
    float* out = (float*)d_out;

    // workspace layout (4B elements):
    //  [0,50000)            deg_out_cnt (int)
    //  [50000,100000)       deg_in_cnt  (int)
    //  [100000,150004)      row_ptr     (int, 50001)
    //  [150004,200004)      cursor      (int)
    //  [200004,1000004)     edge_src    (int)
    //  [1000004,1050004)    excl        (int, scan partial)
    //  [1050004,1050064)    bsum        (int, 49)
    //  [1050112, +6.4M)     xs    -> later ns (overlay; both 128-wide)
    //  [7450112, +6.4M)     agg   -> later p -> later h2 (overlays; p 128-wide)
    //  [13850112, +7.6M)    h1 (ld 152)
    //  total ~21.5M elems ~ 86 MB
    char* wsb = (char*)d_ws;
    int*   deg_out_cnt = (int*)wsb;
    int*   deg_in_cnt  = deg_out_cnt + 50000;
    int*   row_ptr     = deg_out_cnt + 100000;
    int*   cursor      = deg_out_cnt + 150004;
    int*   edge_src    = deg_out_cnt + 200004;
    int*   excl        = deg_out_cnt + 1000004;
    int*   bsum        = deg_out_cnt + 1050004;
    float* xs          = (float*)wsb + 1050112;
    float* agg         = xs + (size_t)N_NODES * D_IN;
    float* h1          = agg + (size_t)N_NODES * D_IN;
    float* ns          = xs;    // overlay: xs dead after gather_x
    float* p           = agg;   // overlay: agg dead after gemm1 (both 6.4M floats)
    float* h2          = agg;   // overlay: p dead after gather_p

    hipMemsetAsync(deg_out_cnt, 0, 100000 * sizeof(int), stream);
    hipMemsetAsync(cursor, 0, 50000 * sizeof(int), stream);

    count_kernel<<<(N_EDGES + 255) / 256, 256, 0, stream>>>(src, dst, deg_out_cnt, deg_in_cnt);
    scan1_kernel<<<N_SBLK, 256, 0, stream>>>(deg_in_cnt, excl, bsum);
    scan2_kernel<<<1, 64, 0, stream>>>(bsum);
    scan3_kernel<<<(N_NODES + 255) / 256, 256, 0, stream>>>(excl, bsum, row_ptr);
    fill_kernel<<<(N_EDGES + 255) / 256, 256, 0, stream>>>(src, dst, row_ptr, cursor, edge_src);
    prescale_kernel<<<(N_NODES * 32 + 255) / 256, 256, 0, stream>>>(x, deg_out_cnt, xs);
    gather_x<<<(N_NODES + 3) / 4, 256, 0, stream>>>(xs, row_ptr, edge_src, agg);

    const int MB = (N_NODES + BM - 1) / BM;   // 391
    // gemm1: h1 = elu(norm_in * (agg @ W1) + b1)   [K=128, N=150]
    gemm_tiled<128, 128, 150, 128, LD1, 1>
        <<<dim3(MB, (150 + BN - 1) / BN), 256, 0, stream>>>(agg, W1, b1, nullptr, deg_in_cnt, h1);
    // gemmP: p = h1 @ Wn   [K=150, N=100, LDC=128 zero-padded for gather_p]
    gemm_tiled<150, 160, 100, LD1, LDP, 0>
        <<<dim3(MB, 2), 256, 0, stream>>>(h1, Wn, nullptr, nullptr, nullptr, p);
    gather_p<<<(N_NODES + 3) / 4, 256, 0, stream>>>(p, row_ptr, edge_src, ns);
    // gemm2: h2 = elu(h1 @ Ws + b2 + ns/deg)        [K=150, N=100]
    gemm_tiled<150, 160, 100, LD1, 100, 2>
        <<<dim3(MB, 2), 256, 0, stream>>>(h1, Ws, b2, ns, deg_in_cnt, h2);
    // gemm3: out = elu(h2 @ W3 + b3)                [K=100, N=64]
    gemm_tiled<100, 112, 64, 100, 64, 3>
        <<<dim3(MB, 1), 256, 0, stream>>>(h2, W3, b3, nullptr, nullptr, out);
}